// Round 6
// baseline (526.953 us; speedup 1.0000x reference)
//
#include <hip/hip_runtime.h>
#include <hip/hip_bf16.h>
#include <math.h>

#define N_NODES 50000
#define N_EDGES 850000
#define IN_DIM  256
#define HD      128      // H1*D
#define H1      4
#define D       32
#define NC      40       // num classes
#define SLOPE   0.2f
#define EPS_BN  1e-5f

#define NBIN    782      // ceil(50000/64) destination bins of 64 nodes
#define BCAP    1536     // slots per bin (mean 1088, sigma ~33 -> 13 sigma headroom)

typedef __attribute__((ext_vector_type(8))) short bf16x8;
typedef __attribute__((ext_vector_type(4))) float f32x4;
typedef unsigned long long u64;

__device__ __forceinline__ unsigned short f2bf(float x) {
    union { float f; unsigned u; } v; v.f = x;
    unsigned r = v.u + 0x7FFF + ((v.u >> 16) & 1);   // RNE
    return (unsigned short)(r >> 16);
}
__device__ __forceinline__ float bf2f(unsigned short h) {
    union { unsigned u; float f; } v; v.u = ((unsigned)h) << 16;
    return v.f;
}
__device__ __forceinline__ uint4 pack8(float a0,float a1,float a2,float a3,
                                       float a4,float a5,float a6,float a7) {
    uint4 p;
    p.x = f2bf(a0) | ((unsigned)f2bf(a1) << 16);
    p.y = f2bf(a2) | ((unsigned)f2bf(a3) << 16);
    p.z = f2bf(a4) | ((unsigned)f2bf(a5) << 16);
    p.w = f2bf(a6) | ((unsigned)f2bf(a7) << 16);
    return p;
}

// chunk-swizzled [rows][32] bf16 tile: 4 chunks of 8 bf16 per row (64B rows).
__device__ __forceinline__ int tile32_addr(int row, int chunk) {
    return row * 32 + ((chunk ^ ((row >> 1) & 3)) << 3);
}

// ---------------------------------------------------------------------------
// binscatter (+ weight cvt): edge e -> tmp[bin*BCAP + cursor] packed (dst,src).
// Bin-local appends keep the active write set at ~782 hot lines.
// Also converts W1->W1t bf16 [128][256] and W2->W2t bf16 [48][128] (pad 0).
// ---------------------------------------------------------------------------
__global__ __launch_bounds__(256) void binscatter_k(const int* __restrict__ src,
                                                    const int* __restrict__ dst,
                                                    int* __restrict__ bincur,
                                                    u64* __restrict__ tmp,
                                                    const float* __restrict__ W1,
                                                    const float* __restrict__ W2,
                                                    unsigned short* __restrict__ W1t,
                                                    unsigned short* __restrict__ W2t) {
    int e = blockIdx.x * blockDim.x + threadIdx.x;
    if (e < IN_DIM * HD) {                 // W1 [256][128] -> W1t [128][256]
        int k = e >> 7, n = e & 127;
        W1t[n * IN_DIM + k] = f2bf(W1[e]);
    }
    if (e < 48 * HD) {                     // W2 [128][40] -> W2t [48][128]
        int n = e >> 7, k = e & 127;
        float v = (n < NC) ? W2[k * NC + n] : 0.f;
        W2t[e] = f2bf(v);
    }
    if (e >= N_EDGES) return;
    int v = dst[e];
    int b = v >> 6;
    int cur = atomicAdd(&bincur[b], 1);
    if (cur < BCAP)
        tmp[(size_t)b * BCAP + cur] = ((u64)v << 32) | (unsigned)src[e];
}

// ---------------------------------------------------------------------------
// binsort: one block per bin. LDS hist over the bin's 64 nodes + shuffle scan
// -> per-node compact ranges; writes csr_src/csr_dst and packed rowp
// (rowp[v] = start | deg<<32). No global scan needed (fixed bin bases).
// ---------------------------------------------------------------------------
__global__ __launch_bounds__(256) void binsort_k(const u64* __restrict__ tmp,
                                                 const int* __restrict__ bincur,
                                                 int* __restrict__ csr_src,
                                                 int* __restrict__ csr_dst,
                                                 u64* __restrict__ rowp) {
    __shared__ int hist[64];
    __shared__ int cur[64];
    int b = blockIdx.x, tid = threadIdx.x;
    int nbase = b << 6;
    size_t base = (size_t)b * BCAP;
    int cnt = min(bincur[b], BCAP);
    if (tid < 64) hist[tid] = 0;
    __syncthreads();
    for (int t = tid; t < cnt; t += 256) {
        int v = (int)(tmp[base + t] >> 32);
        atomicAdd(&hist[v - nbase], 1);
    }
    __syncthreads();
    if (tid < 64) {
        int h = hist[tid];
        int v = h;
        #pragma unroll
        for (int off = 1; off < 64; off <<= 1) {
            int t2 = __shfl_up(v, off);
            if (tid >= off) v += t2;
        }
        int excl = v - h;
        cur[tid] = excl;
        int node = nbase + tid;
        if (node < N_NODES)
            rowp[node] = ((u64)h << 32) | (unsigned)(base + excl);
    }
    __syncthreads();
    for (int t = tid; t < cnt; t += 256) {
        u64 p = tmp[base + t];
        int v = (int)(p >> 32);
        int pos = atomicAdd(&cur[v - nbase], 1);
        csr_src[base + pos] = (int)(p & 0xffffffffu);
        csr_dst[base + pos] = v;
    }
}

// ---------------------------------------------------------------------------
// MFMA GEMM1: ft1b = bf16( bf16(x) @ bf16(W1) ).  M=50000, K=256, N=128.
// ---------------------------------------------------------------------------
__global__ __launch_bounds__(256) void mfma1_k(const float* __restrict__ X,
                                               const unsigned short* __restrict__ W1t,
                                               unsigned short* __restrict__ ftb) {
    __shared__ unsigned short alds[2][64 * 32];
    __shared__ unsigned short wlds[2][128 * 32];
    const int tid = threadIdx.x;
    const int lane = tid & 63, wid = tid >> 6;
    const int wr = wid >> 1, wc = wid & 1;
    const int rowBase = blockIdx.x * 64;
    const int s_arow = tid >> 2, s_ac = tid & 3;
    const int s_wcol = tid >> 1, s_wc0 = (tid & 1) * 2;

    auto stageA = [&](int buf, int ks) {
        float4 v0 = make_float4(0.f,0.f,0.f,0.f), v1 = v0;
        int gr = rowBase + s_arow;
        if (gr < N_NODES) {
            const float4* p = (const float4*)(X + (size_t)gr * IN_DIM + ks * 32 + s_ac * 8);
            v0 = p[0]; v1 = p[1];
        }
        *(uint4*)&alds[buf][tile32_addr(s_arow, s_ac)] =
            pack8(v0.x,v0.y,v0.z,v0.w,v1.x,v1.y,v1.z,v1.w);
    };
    auto stageW = [&](int buf, int ks) {
        const uint4* g = (const uint4*)(W1t + s_wcol * IN_DIM + ks * 32 + s_wc0 * 8);
        uint4 a = g[0], b = g[1];
        *(uint4*)&wlds[buf][tile32_addr(s_wcol, s_wc0)] = a;
        *(uint4*)&wlds[buf][tile32_addr(s_wcol, s_wc0 + 1)] = b;
    };

    f32x4 acc[2][4];
    #pragma unroll
    for (int mf = 0; mf < 2; ++mf)
        #pragma unroll
        for (int nf = 0; nf < 4; ++nf)
            acc[mf][nf] = (f32x4){0.f, 0.f, 0.f, 0.f};

    stageA(0, 0); stageW(0, 0);
    for (int ks = 0; ks < 8; ++ks) {
        __syncthreads();
        if (ks < 7) { stageA((ks + 1) & 1, ks + 1); stageW((ks + 1) & 1, ks + 1); }
        int buf = ks & 1;
        bf16x8 afrag[2], bfrag[4];
        #pragma unroll
        for (int mf = 0; mf < 2; ++mf) {
            int row = wr * 32 + mf * 16 + (lane & 15);
            afrag[mf] = *(const bf16x8*)&alds[buf][tile32_addr(row, lane >> 4)];
        }
        #pragma unroll
        for (int nf = 0; nf < 4; ++nf) {
            int col = wc * 64 + nf * 16 + (lane & 15);
            bfrag[nf] = *(const bf16x8*)&wlds[buf][tile32_addr(col, lane >> 4)];
        }
        #pragma unroll
        for (int mf = 0; mf < 2; ++mf)
            #pragma unroll
            for (int nf = 0; nf < 4; ++nf)
                acc[mf][nf] = __builtin_amdgcn_mfma_f32_16x16x32_bf16(
                    afrag[mf], bfrag[nf], acc[mf][nf], 0, 0, 0);
    }
    #pragma unroll
    for (int mf = 0; mf < 2; ++mf) {
        int r0 = rowBase + wr * 32 + mf * 16 + (lane >> 4) * 4;
        #pragma unroll
        for (int nf = 0; nf < 4; ++nf) {
            int col = wc * 64 + nf * 16 + (lane & 15);
            #pragma unroll
            for (int v = 0; v < 4; ++v) {
                int r = r0 + v;
                if (r < N_NODES) ftb[(size_t)r * HD + col] = f2bf(acc[mf][nf][v]);
            }
        }
    }
}

// ---------------------------------------------------------------------------
// MFMA GEMM2: ft2b = bf16( elu(bn(h1b)) @ W2 ). BN scale/shift computed
// in-block from bnsum/bnsq (bnscale_k folded in).
// ---------------------------------------------------------------------------
__global__ __launch_bounds__(256) void mfma2_k(const unsigned short* __restrict__ Hin,
                                               const unsigned short* __restrict__ W2t,
                                               const float* __restrict__ bnsum,
                                               const float* __restrict__ bnsq,
                                               const float* __restrict__ gamma,
                                               const float* __restrict__ beta,
                                               unsigned short* __restrict__ ft2b) {
    __shared__ unsigned short alds[2][64 * 32];
    __shared__ unsigned short wlds[48 * 128];
    __shared__ float sc_lds[HD], sh_lds[HD];
    const int tid = threadIdx.x;
    const int lane = tid & 63, wid = tid >> 6;
    const int rowBase = blockIdx.x * 64;
    const int s_arow = tid >> 2, s_ac = tid & 3;

    if (tid < HD) {
        const float invN = 1.0f / (float)N_NODES;
        float mu = bnsum[tid] * invN;
        float var = bnsq[tid] * invN - mu * mu;
        float sc = gamma[tid] * rsqrtf(var + EPS_BN);
        sc_lds[tid] = sc;
        sh_lds[tid] = beta[tid] - mu * sc;
    }
    for (int i = tid; i < 48 * 16; i += 256) {
        int col = i >> 4, c = i & 15;
        uint4 v = *(const uint4*)(W2t + col * HD + c * 8);
        *(uint4*)&wlds[col * HD + ((c ^ (col & 7)) << 3)] = v;
    }
    __syncthreads();   // sc/sh + wlds ready

    auto stageA = [&](int buf, int ks) {
        int c0 = ks * 32 + s_ac * 8;
        uint4 pv = make_uint4(0,0,0,0);
        int gr = rowBase + s_arow;
        if (gr < N_NODES) pv = *(const uint4*)(Hin + (size_t)gr * HD + c0);
        float4 sc0 = *(const float4*)(sc_lds + c0), sc1 = *(const float4*)(sc_lds + c0 + 4);
        float4 sh0 = *(const float4*)(sh_lds + c0), sh1 = *(const float4*)(sh_lds + c0 + 4);
        float t[8];
        t[0] = fmaf(bf2f(pv.x & 0xffff), sc0.x, sh0.x);
        t[1] = fmaf(bf2f(pv.x >> 16),    sc0.y, sh0.y);
        t[2] = fmaf(bf2f(pv.y & 0xffff), sc0.z, sh0.z);
        t[3] = fmaf(bf2f(pv.y >> 16),    sc0.w, sh0.w);
        t[4] = fmaf(bf2f(pv.z & 0xffff), sc1.x, sh1.x);
        t[5] = fmaf(bf2f(pv.z >> 16),    sc1.y, sh1.y);
        t[6] = fmaf(bf2f(pv.w & 0xffff), sc1.z, sh1.z);
        t[7] = fmaf(bf2f(pv.w >> 16),    sc1.w, sh1.w);
        #pragma unroll
        for (int i = 0; i < 8; ++i) t[i] = t[i] > 0.f ? t[i] : expm1f(t[i]);
        *(uint4*)&alds[buf][tile32_addr(s_arow, s_ac)] =
            pack8(t[0],t[1],t[2],t[3],t[4],t[5],t[6],t[7]);
    };

    f32x4 acc[3];
    #pragma unroll
    for (int nf = 0; nf < 3; ++nf) acc[nf] = (f32x4){0.f, 0.f, 0.f, 0.f};

    stageA(0, 0);
    for (int ks = 0; ks < 4; ++ks) {
        __syncthreads();
        if (ks < 3) stageA((ks + 1) & 1, ks + 1);
        int buf = ks & 1;
        int row = wid * 16 + (lane & 15);
        bf16x8 a = *(const bf16x8*)&alds[buf][tile32_addr(row, lane >> 4)];
        #pragma unroll
        for (int nf = 0; nf < 3; ++nf) {
            int col = nf * 16 + (lane & 15);
            int c = ks * 4 + (lane >> 4);
            bf16x8 b = *(const bf16x8*)&wlds[col * HD + ((c ^ (col & 7)) << 3)];
            acc[nf] = __builtin_amdgcn_mfma_f32_16x16x32_bf16(a, b, acc[nf], 0, 0, 0);
        }
    }
    int r0 = rowBase + wid * 16 + (lane >> 4) * 4;
    #pragma unroll
    for (int nf = 0; nf < 3; ++nf) {
        int col = nf * 16 + (lane & 15);
        if (col < NC) {
            #pragma unroll
            for (int v = 0; v < 4; ++v) {
                int r = r0 + v;
                if (r < N_NODES) ft2b[(size_t)r * NC + col] = f2bf(acc[nf][v]);
            }
        }
    }
}

// ---------------------------------------------------------------------------
// el/er layer 1 from bf16 features
// ---------------------------------------------------------------------------
__global__ void eler1b_k(const unsigned short* __restrict__ ftb,
                         const float* __restrict__ alw, const float* __restrict__ arw,
                         float* __restrict__ el, float* __restrict__ er) {
    int t = blockIdx.x * blockDim.x + threadIdx.x;
    if (t >= N_NODES * H1) return;
    int n = t >> 2, h = t & 3;
    const unsigned short* f = ftb + (size_t)n * HD + h * D;
    const float* a = alw + h * D;
    const float* r = arw + h * D;
    float sl = 0.f, sr = 0.f;
    #pragma unroll
    for (int d = 0; d < D; d += 8) {
        uint4 fv = *(const uint4*)(f + d);
        float x0 = bf2f(fv.x & 0xffff), x1 = bf2f(fv.x >> 16);
        float x2 = bf2f(fv.y & 0xffff), x3 = bf2f(fv.y >> 16);
        float x4 = bf2f(fv.z & 0xffff), x5 = bf2f(fv.z >> 16);
        float x6 = bf2f(fv.w & 0xffff), x7 = bf2f(fv.w >> 16);
        sl += x0*a[d] + x1*a[d+1] + x2*a[d+2] + x3*a[d+3]
            + x4*a[d+4] + x5*a[d+5] + x6*a[d+6] + x7*a[d+7];
        sr += x0*r[d] + x1*r[d+1] + x2*r[d+2] + x3*r[d+3]
            + x4*r[d+4] + x5*r[d+5] + x6*r[d+6] + x7*r[d+7];
    }
    el[t] = sl; er[t] = sr;
}

// el/er for layer 2 from bf16 ft2
__global__ void eler2b_k(const unsigned short* __restrict__ ft2b,
                         const float* __restrict__ alw, const float* __restrict__ arw,
                         float* __restrict__ el, float* __restrict__ er) {
    int n = blockIdx.x * blockDim.x + threadIdx.x;
    if (n >= N_NODES) return;
    const unsigned short* f = ft2b + (size_t)n * NC;
    float sl = 0.f, sr = 0.f;
    #pragma unroll
    for (int d = 0; d < NC; d += 4) {
        uint2 fv = *(const uint2*)(f + d);
        float x0 = bf2f(fv.x & 0xffff), x1 = bf2f(fv.x >> 16);
        float x2 = bf2f(fv.y & 0xffff), x3 = bf2f(fv.y >> 16);
        sl += x0*alw[d] + x1*alw[d+1] + x2*alw[d+2] + x3*alw[d+3];
        sr += x0*arw[d] + x1*arw[d+1] + x2*arw[d+2] + x3*arw[d+3];
    }
    el[n] = sl; er[n] = sr;
}

// ---------------------------------------------------------------------------
// Edge-weight precompute over bin-slot space: exw1[slot][h] / exw2[slot]
// ---------------------------------------------------------------------------
__global__ void exw1_k(const int* __restrict__ csr_src, const int* __restrict__ csr_dst,
                       const int* __restrict__ bincur,
                       const float* __restrict__ el, const float* __restrict__ er,
                       float4* __restrict__ exw) {
    int s = blockIdx.x * blockDim.x + threadIdx.x;
    int b = s / BCAP;
    int off = s - b * BCAP;
    if (off >= min(bincur[b], BCAP)) return;
    int u = csr_src[s], v = csr_dst[s];
    const float4 l = *(const float4*)(el + u * H1);
    const float4 r = *(const float4*)(er + v * H1);
    float4 o;
    float t;
    t = l.x + r.x; t = t > 0.f ? t : SLOPE * t; o.x = __expf(t);
    t = l.y + r.y; t = t > 0.f ? t : SLOPE * t; o.y = __expf(t);
    t = l.z + r.z; t = t > 0.f ? t : SLOPE * t; o.z = __expf(t);
    t = l.w + r.w; t = t > 0.f ? t : SLOPE * t; o.w = __expf(t);
    exw[s] = o;
}

__global__ void exw2_k(const int* __restrict__ csr_src, const int* __restrict__ csr_dst,
                       const int* __restrict__ bincur,
                       const float* __restrict__ el, const float* __restrict__ er,
                       float* __restrict__ exw) {
    int s = blockIdx.x * blockDim.x + threadIdx.x;
    int b = s / BCAP;
    int off = s - b * BCAP;
    if (off >= min(bincur[b], BCAP)) return;
    float t = el[csr_src[s]] + er[csr_dst[s]];
    t = t > 0.f ? t : SLOPE * t;
    exw[s] = __expf(t);
}

// ---------------------------------------------------------------------------
// layer-1 gather: one wave per dst node; lane owns bf16x2 of 128 dims.
// rowp packed (start | deg<<32). Writes bf16 h1.
// ---------------------------------------------------------------------------
__global__ __launch_bounds__(256) void gather1_k(const u64* __restrict__ rowp,
                                                 const int* __restrict__ csr_src,
                                                 const float* __restrict__ exw,
                                                 const unsigned short* __restrict__ ftb,
                                                 unsigned int* __restrict__ h1b) {
    int w = (blockIdx.x * blockDim.x + threadIdx.x) >> 6;   // node
    if (w >= N_NODES) return;
    int lane = threadIdx.x & 63;
    int hh = lane >> 4;
    u64 rp = rowp[w];
    int jb = (int)(rp & 0xffffffffu), je = jb + (int)(rp >> 32);
    float ax = 0.f, ay = 0.f, ssum = 0.f;
    int j = jb;
    for (; j + 3 < je; j += 4) {
        int u0 = csr_src[j], u1 = csr_src[j+1], u2 = csr_src[j+2], u3 = csr_src[j+3];
        float w0 = exw[(size_t)j*H1 + hh];
        float w1 = exw[(size_t)(j+1)*H1 + hh];
        float w2 = exw[(size_t)(j+2)*H1 + hh];
        float w3 = exw[(size_t)(j+3)*H1 + hh];
        ushort2 f0 = *(const ushort2*)(ftb + (size_t)u0 * HD + lane * 2);
        ushort2 f1 = *(const ushort2*)(ftb + (size_t)u1 * HD + lane * 2);
        ushort2 f2 = *(const ushort2*)(ftb + (size_t)u2 * HD + lane * 2);
        ushort2 f3 = *(const ushort2*)(ftb + (size_t)u3 * HD + lane * 2);
        ax = fmaf(w0, bf2f(f0.x), ax); ay = fmaf(w0, bf2f(f0.y), ay);
        ax = fmaf(w1, bf2f(f1.x), ax); ay = fmaf(w1, bf2f(f1.y), ay);
        ax = fmaf(w2, bf2f(f2.x), ax); ay = fmaf(w2, bf2f(f2.y), ay);
        ax = fmaf(w3, bf2f(f3.x), ax); ay = fmaf(w3, bf2f(f3.y), ay);
        ssum += (w0 + w1) + (w2 + w3);
    }
    for (; j < je; ++j) {
        int u0 = csr_src[j];
        float w0 = exw[(size_t)j*H1 + hh];
        ushort2 f0 = *(const ushort2*)(ftb + (size_t)u0 * HD + lane * 2);
        ax = fmaf(w0, bf2f(f0.x), ax); ay = fmaf(w0, bf2f(f0.y), ay);
        ssum += w0;
    }
    float inv = 1.0f / fmaxf(ssum, 1e-9f);
    h1b[(size_t)w * 64 + lane] = (unsigned)f2bf(ax * inv)
                               | ((unsigned)f2bf(ay * inv) << 16);
}

// ---------------------------------------------------------------------------
// BN stats on bf16 h1
// ---------------------------------------------------------------------------
__global__ void bnstats_k(const unsigned short* __restrict__ h1b,
                          float* __restrict__ sums, float* __restrict__ sumsq) {
    int c = threadIdx.x;  // 128 threads
    float acc = 0.f, acc2 = 0.f;
    for (int r = blockIdx.x; r < N_NODES; r += gridDim.x) {
        float v = bf2f(h1b[(size_t)r * HD + c]);
        acc += v; acc2 += v * v;
    }
    atomicAdd(&sums[c], acc);
    atomicAdd(&sumsq[c], acc2);
}

// ---------------------------------------------------------------------------
// layer-2 gather fused with log_softmax
// ---------------------------------------------------------------------------
__global__ __launch_bounds__(256) void gather2_k(const u64* __restrict__ rowp,
                                                 const int* __restrict__ csr_src,
                                                 const float* __restrict__ exw,
                                                 const unsigned short* __restrict__ ft2b,
                                                 float* __restrict__ out) {
    int w = (blockIdx.x * blockDim.x + threadIdx.x) >> 6;   // node
    if (w >= N_NODES) return;
    int lane = threadIdx.x & 63;
    u64 rp = rowp[w];
    int jb = (int)(rp & 0xffffffffu), je = jb + (int)(rp >> 32);
    float acc = 0.f, ssum = 0.f;
    int j = jb;
    for (; j + 3 < je; j += 4) {
        int u0 = csr_src[j], u1 = csr_src[j+1], u2 = csr_src[j+2], u3 = csr_src[j+3];
        float w0 = exw[j], w1 = exw[j+1], w2 = exw[j+2], w3 = exw[j+3];
        float fa = (lane < NC) ? bf2f(ft2b[(size_t)u0 * NC + lane]) : 0.f;
        float fb = (lane < NC) ? bf2f(ft2b[(size_t)u1 * NC + lane]) : 0.f;
        float fc = (lane < NC) ? bf2f(ft2b[(size_t)u2 * NC + lane]) : 0.f;
        float fd = (lane < NC) ? bf2f(ft2b[(size_t)u3 * NC + lane]) : 0.f;
        acc = fmaf(w0, fa, acc); acc = fmaf(w1, fb, acc);
        acc = fmaf(w2, fc, acc); acc = fmaf(w3, fd, acc);
        ssum += (w0 + w1) + (w2 + w3);
    }
    for (; j < je; ++j) {
        int u0 = csr_src[j];
        float w0 = exw[j];
        float fa = (lane < NC) ? bf2f(ft2b[(size_t)u0 * NC + lane]) : 0.f;
        acc = fmaf(w0, fa, acc);
        ssum += w0;
    }
    float v = acc / fmaxf(ssum, 1e-9f);
    float vv = (lane < NC) ? v : -INFINITY;
    float m = vv;
    #pragma unroll
    for (int off = 32; off; off >>= 1) m = fmaxf(m, __shfl_xor(m, off));
    float ex2 = (lane < NC) ? __expf(vv - m) : 0.f;
    float sum = ex2;
    #pragma unroll
    for (int off = 32; off; off >>= 1) sum += __shfl_xor(sum, off);
    if (lane < NC) out[(size_t)w * NC + lane] = vv - m - logf(sum);
}

// ---------------------------------------------------------------------------
extern "C" void kernel_launch(void* const* d_in, const int* in_sizes, int n_in,
                              void* d_out, int out_size, void* d_ws, size_t ws_size,
                              hipStream_t stream) {
    const float* x     = (const float*)d_in[0];
    const int*   src   = (const int*)  d_in[1];
    const int*   dst   = (const int*)  d_in[2];
    const float* W1    = (const float*)d_in[3];
    const float* al1   = (const float*)d_in[4];
    const float* ar1   = (const float*)d_in[5];
    const float* gamma = (const float*)d_in[6];
    const float* beta  = (const float*)d_in[7];
    const float* W2    = (const float*)d_in[8];
    const float* al2   = (const float*)d_in[9];
    const float* ar2   = (const float*)d_in[10];
    float* out = (float*)d_out;

    const size_t NSLOT = (size_t)NBIN * BCAP;   // 1,201,152

    char* ws = (char*)d_ws;
    size_t o = 0;
    auto allocB = [&](size_t bytes) { void* p = ws + o; o += (bytes + 15) & ~15ull; return p; };
    // ---- zeroed region (one tiny memset) ----
    int*   bincur = (int*)allocB(NBIN * 4);
    float* bnsum  = (float*)allocB(HD * 4);
    float* bnsq   = (float*)allocB(HD * 4);
    size_t zeroBytes = o;
    // ---- uninitialized region ----
    u64*   tmp     = (u64*)allocB(NSLOT * 8);
    int*   csr_src = (int*)allocB(NSLOT * 4);
    int*   csr_dst = (int*)allocB(NSLOT * 4);
    u64*   rowp    = (u64*)allocB((size_t)N_NODES * 8);
    float4* exw1   = (float4*)allocB(NSLOT * 16);
    float*  exw2   = (float*)allocB(NSLOT * 4);
    unsigned short* w1t  = (unsigned short*)allocB((size_t)IN_DIM * HD * 2);
    unsigned short* w2t  = (unsigned short*)allocB((size_t)48 * HD * 2);
    unsigned short* ft1b = (unsigned short*)allocB((size_t)N_NODES * HD * 2);
    unsigned int*   h1b  = (unsigned int*)allocB((size_t)N_NODES * HD * 2);
    float* el1  = (float*)allocB(N_NODES * H1 * 4);
    float* er1  = (float*)allocB(N_NODES * H1 * 4);
    unsigned short* ft2b = (unsigned short*)allocB((size_t)N_NODES * NC * 2);
    float* el2  = (float*)allocB(N_NODES * 4);
    float* er2  = (float*)allocB(N_NODES * 4);

    hipMemsetAsync(d_ws, 0, zeroBytes, stream);

    const int NB_E    = (N_EDGES + 255) / 256;            // 3321
    const int NB_G    = (N_NODES + 63) / 64;              // 782
    const int NB_S    = (int)(NSLOT / 256);               // 4692 (BCAP%256==0)

    // CSR build (binned) + weight cvt
    binscatter_k<<<NB_E, 256, 0, stream>>>(src, dst, bincur, tmp, W1, W2, w1t, w2t);
    binsort_k<<<NBIN, 256, 0, stream>>>(tmp, bincur, csr_src, csr_dst, rowp);

    // layer 1
    mfma1_k<<<NB_G, 256, 0, stream>>>(x, w1t, ft1b);
    eler1b_k<<<(N_NODES * H1 + 255) / 256, 256, 0, stream>>>(ft1b, al1, ar1, el1, er1);
    exw1_k<<<NB_S, 256, 0, stream>>>(csr_src, csr_dst, bincur, el1, er1, exw1);
    gather1_k<<<N_NODES / 4, 256, 0, stream>>>(rowp, csr_src, (const float*)exw1, ft1b, h1b);

    bnstats_k<<<512, HD, 0, stream>>>((const unsigned short*)h1b, bnsum, bnsq);

    // layer 2 (BN fold + ELU fused into GEMM2 A-staging)
    mfma2_k<<<NB_G, 256, 0, stream>>>((const unsigned short*)h1b, w2t,
                                      bnsum, bnsq, gamma, beta, ft2b);
    eler2b_k<<<(N_NODES + 255) / 256, 256, 0, stream>>>(ft2b, al2, ar2, el2, er2);
    exw2_k<<<NB_S, 256, 0, stream>>>(csr_src, csr_dst, bincur, el2, er2, exw2);
    gather2_k<<<N_NODES / 4, 256, 0, stream>>>(rowp, csr_src, exw2, ft2b, out);
}

// Round 9
// 352.801 us; speedup vs baseline: 1.4936x; 1.4936x over previous
//
#include <hip/hip_runtime.h>
#include <hip/hip_bf16.h>
#include <math.h>

#define N_NODES 50000
#define N_EDGES 850000
#define IN_DIM  256
#define HD      128      // H1*D
#define H1      4
#define D       32
#define NC      40       // num classes
#define SLOPE   0.2f
#define EPS_BN  1e-5f

#define NBIN    782      // ceil(50000/64) destination bins of 64 nodes
#define BCAP    1536     // compact slots per bin (mean 1088, sigma ~33)
#define NREP    32       // cursor replicas per bin (kills atomic contention)
#define RCAP    128      // slots per (bin,replica): rep=e&31 -> mean 34, sigma 5.8
#define NWAVE   4        // waves per 256-thread block (binsort strides by THIS)

typedef __attribute__((ext_vector_type(8))) short bf16x8;
typedef __attribute__((ext_vector_type(4))) float f32x4;
typedef unsigned long long u64;

__device__ __forceinline__ unsigned short f2bf(float x) {
    union { float f; unsigned u; } v; v.f = x;
    unsigned r = v.u + 0x7FFF + ((v.u >> 16) & 1);   // RNE
    return (unsigned short)(r >> 16);
}
__device__ __forceinline__ float bf2f(unsigned short h) {
    union { unsigned u; float f; } v; v.u = ((unsigned)h) << 16;
    return v.f;
}
__device__ __forceinline__ uint4 pack8(float a0,float a1,float a2,float a3,
                                       float a4,float a5,float a6,float a7) {
    uint4 p;
    p.x = f2bf(a0) | ((unsigned)f2bf(a1) << 16);
    p.y = f2bf(a2) | ((unsigned)f2bf(a3) << 16);
    p.z = f2bf(a4) | ((unsigned)f2bf(a5) << 16);
    p.w = f2bf(a6) | ((unsigned)f2bf(a7) << 16);
    return p;
}

// chunk-swizzled [rows][32] bf16 tile: 4 chunks of 8 bf16 per row (64B rows).
__device__ __forceinline__ int tile32_addr(int row, int chunk) {
    return row * 32 + ((chunk ^ ((row >> 1) & 3)) << 3);
}

// ---------------------------------------------------------------------------
// binscatter (+ weight cvt): edge e -> tmp[(bin*NREP + (e&31))*RCAP + cur]
// packed u32 (dlow<<16 | src). 25k sharded cursors, ~34 hits each.
// ---------------------------------------------------------------------------
__global__ __launch_bounds__(256) void binscatter_k(const int* __restrict__ src,
                                                    const int* __restrict__ dst,
                                                    int* __restrict__ bincur,
                                                    unsigned* __restrict__ tmp,
                                                    const float* __restrict__ W1,
                                                    const float* __restrict__ W2,
                                                    unsigned short* __restrict__ W1t,
                                                    unsigned short* __restrict__ W2t) {
    int e = blockIdx.x * blockDim.x + threadIdx.x;
    if (e < IN_DIM * HD) {                 // W1 [256][128] -> W1t [128][256]
        int k = e >> 7, n = e & 127;
        W1t[n * IN_DIM + k] = f2bf(W1[e]);
    }
    if (e < 48 * HD) {                     // W2 [128][40] -> W2t [48][128]
        int n = e >> 7, k = e & 127;
        float v = (n < NC) ? W2[k * NC + n] : 0.f;
        W2t[e] = f2bf(v);
    }
    if (e >= N_EDGES) return;
    int v = dst[e];
    int b = v >> 6;
    int rep = e & (NREP - 1);              // edge-id based: decorrelated from data order
    int cell = b * NREP + rep;
    int cur = atomicAdd(&bincur[cell], 1);
    if (cur < RCAP)
        tmp[(size_t)cell * RCAP + cur] = ((unsigned)(v & 63) << 16) | (unsigned)src[e];
}

// ---------------------------------------------------------------------------
// binsort: one block (4 waves) per bin. Reads the bin's 32 ragged segments
// (wave wv owns s = wv, wv+4, ...), LDS hist over 64 nodes + wave scan ->
// compact csrp, packed rowp (start | deg<<32), bintot.
// ---------------------------------------------------------------------------
__global__ __launch_bounds__(256) void binsort_k(const unsigned* __restrict__ tmp,
                                                 const int* __restrict__ bincur,
                                                 unsigned* __restrict__ csrp,
                                                 u64* __restrict__ rowp,
                                                 int* __restrict__ bintot) {
    __shared__ int cnts[NREP];
    __shared__ int hist[64];
    __shared__ int cur[64];
    int b = blockIdx.x, tid = threadIdx.x;
    int nbase = b << 6;
    size_t cbase = (size_t)b * BCAP;
    int wv = tid >> 6, ln = tid & 63;
    if (tid < NREP) cnts[tid] = min(bincur[b * NREP + tid], RCAP);
    if (tid < 64) hist[tid] = 0;
    __syncthreads();
    // pass 1: histogram (stride = NWAVE waves!)
    for (int s = wv; s < NREP; s += NWAVE) {
        int c = cnts[s];
        const unsigned* seg = tmp + (size_t)(b * NREP + s) * RCAP;
        for (int t = ln; t < c; t += 64)
            atomicAdd(&hist[seg[t] >> 16], 1);
    }
    __syncthreads();
    if (tid < 64) {
        int h = hist[tid];
        int v = h;
        #pragma unroll
        for (int off = 1; off < 64; off <<= 1) {
            int t2 = __shfl_up(v, off);
            if (tid >= off) v += t2;
        }
        int excl = v - h;
        cur[tid] = excl;
        int node = nbase + tid;
        if (node < N_NODES)
            rowp[node] = ((u64)h << 32) | (unsigned)(cbase + excl);
        if (tid == 63) bintot[b] = v;
    }
    __syncthreads();
    // pass 2: scatter into compact bin region (stride = NWAVE)
    for (int s = wv; s < NREP; s += NWAVE) {
        int c = cnts[s];
        const unsigned* seg = tmp + (size_t)(b * NREP + s) * RCAP;
        for (int t = ln; t < c; t += 64) {
            unsigned p = seg[t];
            int pos = atomicAdd(&cur[p >> 16], 1);
            csrp[cbase + pos] = p;
        }
    }
}

// ---------------------------------------------------------------------------
// MFMA GEMM1: ft1b = bf16( bf16(x) @ bf16(W1) ).  M=50000, K=256, N=128.
// ---------------------------------------------------------------------------
__global__ __launch_bounds__(256) void mfma1_k(const float* __restrict__ X,
                                               const unsigned short* __restrict__ W1t,
                                               unsigned short* __restrict__ ftb) {
    __shared__ unsigned short alds[2][64 * 32];
    __shared__ unsigned short wlds[2][128 * 32];
    const int tid = threadIdx.x;
    const int lane = tid & 63, wid = tid >> 6;
    const int wr = wid >> 1, wc = wid & 1;
    const int rowBase = blockIdx.x * 64;
    const int s_arow = tid >> 2, s_ac = tid & 3;
    const int s_wcol = tid >> 1, s_wc0 = (tid & 1) * 2;

    auto stageA = [&](int buf, int ks) {
        float4 v0 = make_float4(0.f,0.f,0.f,0.f), v1 = v0;
        int gr = rowBase + s_arow;
        if (gr < N_NODES) {
            const float4* p = (const float4*)(X + (size_t)gr * IN_DIM + ks * 32 + s_ac * 8);
            v0 = p[0]; v1 = p[1];
        }
        *(uint4*)&alds[buf][tile32_addr(s_arow, s_ac)] =
            pack8(v0.x,v0.y,v0.z,v0.w,v1.x,v1.y,v1.z,v1.w);
    };
    auto stageW = [&](int buf, int ks) {
        const uint4* g = (const uint4*)(W1t + s_wcol * IN_DIM + ks * 32 + s_wc0 * 8);
        uint4 a = g[0], b = g[1];
        *(uint4*)&wlds[buf][tile32_addr(s_wcol, s_wc0)] = a;
        *(uint4*)&wlds[buf][tile32_addr(s_wcol, s_wc0 + 1)] = b;
    };

    f32x4 acc[2][4];
    #pragma unroll
    for (int mf = 0; mf < 2; ++mf)
        #pragma unroll
        for (int nf = 0; nf < 4; ++nf)
            acc[mf][nf] = (f32x4){0.f, 0.f, 0.f, 0.f};

    stageA(0, 0); stageW(0, 0);
    for (int ks = 0; ks < 8; ++ks) {
        __syncthreads();
        if (ks < 7) { stageA((ks + 1) & 1, ks + 1); stageW((ks + 1) & 1, ks + 1); }
        int buf = ks & 1;
        bf16x8 afrag[2], bfrag[4];
        #pragma unroll
        for (int mf = 0; mf < 2; ++mf) {
            int row = wr * 32 + mf * 16 + (lane & 15);
            afrag[mf] = *(const bf16x8*)&alds[buf][tile32_addr(row, lane >> 4)];
        }
        #pragma unroll
        for (int nf = 0; nf < 4; ++nf) {
            int col = wc * 64 + nf * 16 + (lane & 15);
            bfrag[nf] = *(const bf16x8*)&wlds[buf][tile32_addr(col, lane >> 4)];
        }
        #pragma unroll
        for (int mf = 0; mf < 2; ++mf)
            #pragma unroll
            for (int nf = 0; nf < 4; ++nf)
                acc[mf][nf] = __builtin_amdgcn_mfma_f32_16x16x32_bf16(
                    afrag[mf], bfrag[nf], acc[mf][nf], 0, 0, 0);
    }
    #pragma unroll
    for (int mf = 0; mf < 2; ++mf) {
        int r0 = rowBase + wr * 32 + mf * 16 + (lane >> 4) * 4;
        #pragma unroll
        for (int nf = 0; nf < 4; ++nf) {
            int col = wc * 64 + nf * 16 + (lane & 15);
            #pragma unroll
            for (int v = 0; v < 4; ++v) {
                int r = r0 + v;
                if (r < N_NODES) ftb[(size_t)r * HD + col] = f2bf(acc[mf][nf][v]);
            }
        }
    }
}

// ---------------------------------------------------------------------------
// MFMA GEMM2: ft2b = bf16( elu(bn(h1b)) @ W2 ). BN fold in prologue.
// ---------------------------------------------------------------------------
__global__ __launch_bounds__(256) void mfma2_k(const unsigned short* __restrict__ Hin,
                                               const unsigned short* __restrict__ W2t,
                                               const float* __restrict__ bnsum,
                                               const float* __restrict__ bnsq,
                                               const float* __restrict__ gamma,
                                               const float* __restrict__ beta,
                                               unsigned short* __restrict__ ft2b) {
    __shared__ unsigned short alds[2][64 * 32];
    __shared__ unsigned short wlds[48 * 128];
    __shared__ float sc_lds[HD], sh_lds[HD];
    const int tid = threadIdx.x;
    const int lane = tid & 63, wid = tid >> 6;
    const int rowBase = blockIdx.x * 64;
    const int s_arow = tid >> 2, s_ac = tid & 3;

    if (tid < HD) {
        const float invN = 1.0f / (float)N_NODES;
        float mu = bnsum[tid] * invN;
        float var = bnsq[tid] * invN - mu * mu;
        float sc = gamma[tid] * rsqrtf(var + EPS_BN);
        sc_lds[tid] = sc;
        sh_lds[tid] = beta[tid] - mu * sc;
    }
    for (int i = tid; i < 48 * 16; i += 256) {
        int col = i >> 4, c = i & 15;
        uint4 v = *(const uint4*)(W2t + col * HD + c * 8);
        *(uint4*)&wlds[col * HD + ((c ^ (col & 7)) << 3)] = v;
    }
    __syncthreads();

    auto stageA = [&](int buf, int ks) {
        int c0 = ks * 32 + s_ac * 8;
        uint4 pv = make_uint4(0,0,0,0);
        int gr = rowBase + s_arow;
        if (gr < N_NODES) pv = *(const uint4*)(Hin + (size_t)gr * HD + c0);
        float4 sc0 = *(const float4*)(sc_lds + c0), sc1 = *(const float4*)(sc_lds + c0 + 4);
        float4 sh0 = *(const float4*)(sh_lds + c0), sh1 = *(const float4*)(sh_lds + c0 + 4);
        float t[8];
        t[0] = fmaf(bf2f(pv.x & 0xffff), sc0.x, sh0.x);
        t[1] = fmaf(bf2f(pv.x >> 16),    sc0.y, sh0.y);
        t[2] = fmaf(bf2f(pv.y & 0xffff), sc0.z, sh0.z);
        t[3] = fmaf(bf2f(pv.y >> 16),    sc0.w, sh0.w);
        t[4] = fmaf(bf2f(pv.z & 0xffff), sc1.x, sh1.x);
        t[5] = fmaf(bf2f(pv.z >> 16),    sc1.y, sh1.y);
        t[6] = fmaf(bf2f(pv.w & 0xffff), sc1.z, sh1.z);
        t[7] = fmaf(bf2f(pv.w >> 16),    sc1.w, sh1.w);
        #pragma unroll
        for (int i = 0; i < 8; ++i) t[i] = t[i] > 0.f ? t[i] : expm1f(t[i]);
        *(uint4*)&alds[buf][tile32_addr(s_arow, s_ac)] =
            pack8(t[0],t[1],t[2],t[3],t[4],t[5],t[6],t[7]);
    };

    f32x4 acc[3];
    #pragma unroll
    for (int nf = 0; nf < 3; ++nf) acc[nf] = (f32x4){0.f, 0.f, 0.f, 0.f};

    stageA(0, 0);
    for (int ks = 0; ks < 4; ++ks) {
        __syncthreads();
        if (ks < 3) stageA((ks + 1) & 1, ks + 1);
        int buf = ks & 1;
        int row = wid * 16 + (lane & 15);
        bf16x8 a = *(const bf16x8*)&alds[buf][tile32_addr(row, lane >> 4)];
        #pragma unroll
        for (int nf = 0; nf < 3; ++nf) {
            int col = nf * 16 + (lane & 15);
            int c = ks * 4 + (lane >> 4);
            bf16x8 b = *(const bf16x8*)&wlds[col * HD + ((c ^ (col & 7)) << 3)];
            acc[nf] = __builtin_amdgcn_mfma_f32_16x16x32_bf16(a, b, acc[nf], 0, 0, 0);
        }
    }
    int r0 = rowBase + wid * 16 + (lane >> 4) * 4;
    #pragma unroll
    for (int nf = 0; nf < 3; ++nf) {
        int col = nf * 16 + (lane & 15);
        if (col < NC) {
            #pragma unroll
            for (int v = 0; v < 4; ++v) {
                int r = r0 + v;
                if (r < N_NODES) ft2b[(size_t)r * NC + col] = f2bf(acc[nf][v]);
            }
        }
    }
}

// ---------------------------------------------------------------------------
// el/er layer 1 from bf16 features
// ---------------------------------------------------------------------------
__global__ void eler1b_k(const unsigned short* __restrict__ ftb,
                         const float* __restrict__ alw, const float* __restrict__ arw,
                         float* __restrict__ el, float* __restrict__ er) {
    int t = blockIdx.x * blockDim.x + threadIdx.x;
    if (t >= N_NODES * H1) return;
    int n = t >> 2, h = t & 3;
    const unsigned short* f = ftb + (size_t)n * HD + h * D;
    const float* a = alw + h * D;
    const float* r = arw + h * D;
    float sl = 0.f, sr = 0.f;
    #pragma unroll
    for (int d = 0; d < D; d += 8) {
        uint4 fv = *(const uint4*)(f + d);
        float x0 = bf2f(fv.x & 0xffff), x1 = bf2f(fv.x >> 16);
        float x2 = bf2f(fv.y & 0xffff), x3 = bf2f(fv.y >> 16);
        float x4 = bf2f(fv.z & 0xffff), x5 = bf2f(fv.z >> 16);
        float x6 = bf2f(fv.w & 0xffff), x7 = bf2f(fv.w >> 16);
        sl += x0*a[d] + x1*a[d+1] + x2*a[d+2] + x3*a[d+3]
            + x4*a[d+4] + x5*a[d+5] + x6*a[d+6] + x7*a[d+7];
        sr += x0*r[d] + x1*r[d+1] + x2*r[d+2] + x3*r[d+3]
            + x4*r[d+4] + x5*r[d+5] + x6*r[d+6] + x7*r[d+7];
    }
    el[t] = sl; er[t] = sr;
}

// el/er for layer 2 from bf16 ft2
__global__ void eler2b_k(const unsigned short* __restrict__ ft2b,
                         const float* __restrict__ alw, const float* __restrict__ arw,
                         float* __restrict__ el, float* __restrict__ er) {
    int n = blockIdx.x * blockDim.x + threadIdx.x;
    if (n >= N_NODES) return;
    const unsigned short* f = ft2b + (size_t)n * NC;
    float sl = 0.f, sr = 0.f;
    #pragma unroll
    for (int d = 0; d < NC; d += 4) {
        uint2 fv = *(const uint2*)(f + d);
        float x0 = bf2f(fv.x & 0xffff), x1 = bf2f(fv.x >> 16);
        float x2 = bf2f(fv.y & 0xffff), x3 = bf2f(fv.y >> 16);
        sl += x0*alw[d] + x1*alw[d+1] + x2*alw[d+2] + x3*alw[d+3];
        sr += x0*arw[d] + x1*arw[d+1] + x2*arw[d+2] + x3*arw[d+3];
    }
    el[n] = sl; er[n] = sr;
}

// ---------------------------------------------------------------------------
// Edge-weight precompute over bin-slot space (u,v unpacked from csrp)
// ---------------------------------------------------------------------------
__global__ void exw1_k(const unsigned* __restrict__ csrp,
                       const int* __restrict__ bintot,
                       const float* __restrict__ el, const float* __restrict__ er,
                       float4* __restrict__ exw) {
    int s = blockIdx.x * blockDim.x + threadIdx.x;
    int b = s / BCAP;
    int off = s - b * BCAP;
    if (off >= bintot[b]) return;
    unsigned p = csrp[s];
    int u = p & 0xffff;
    int v = (b << 6) + (p >> 16);
    const float4 l = *(const float4*)(el + u * H1);
    const float4 r = *(const float4*)(er + v * H1);
    float4 o;
    float t;
    t = l.x + r.x; t = t > 0.f ? t : SLOPE * t; o.x = __expf(t);
    t = l.y + r.y; t = t > 0.f ? t : SLOPE * t; o.y = __expf(t);
    t = l.z + r.z; t = t > 0.f ? t : SLOPE * t; o.z = __expf(t);
    t = l.w + r.w; t = t > 0.f ? t : SLOPE * t; o.w = __expf(t);
    exw[s] = o;
}

__global__ void exw2_k(const unsigned* __restrict__ csrp,
                       const int* __restrict__ bintot,
                       const float* __restrict__ el, const float* __restrict__ er,
                       float* __restrict__ exw) {
    int s = blockIdx.x * blockDim.x + threadIdx.x;
    int b = s / BCAP;
    int off = s - b * BCAP;
    if (off >= bintot[b]) return;
    unsigned p = csrp[s];
    float t = el[p & 0xffff] + er[(b << 6) + (p >> 16)];
    t = t > 0.f ? t : SLOPE * t;
    exw[s] = __expf(t);
}

// ---------------------------------------------------------------------------
// layer-1 gather: one wave per dst node; lane owns bf16x2 of 128 dims.
// ---------------------------------------------------------------------------
__global__ __launch_bounds__(256) void gather1_k(const u64* __restrict__ rowp,
                                                 const unsigned* __restrict__ csrp,
                                                 const float* __restrict__ exw,
                                                 const unsigned short* __restrict__ ftb,
                                                 unsigned int* __restrict__ h1b) {
    int w = (blockIdx.x * blockDim.x + threadIdx.x) >> 6;   // node
    if (w >= N_NODES) return;
    int lane = threadIdx.x & 63;
    int hh = lane >> 4;
    u64 rp = rowp[w];
    int jb = (int)(rp & 0xffffffffu), je = jb + (int)(rp >> 32);
    float ax = 0.f, ay = 0.f, ssum = 0.f;
    int j = jb;
    for (; j + 3 < je; j += 4) {
        int u0 = csrp[j] & 0xffff, u1 = csrp[j+1] & 0xffff;
        int u2 = csrp[j+2] & 0xffff, u3 = csrp[j+3] & 0xffff;
        float w0 = exw[(size_t)j*H1 + hh];
        float w1 = exw[(size_t)(j+1)*H1 + hh];
        float w2 = exw[(size_t)(j+2)*H1 + hh];
        float w3 = exw[(size_t)(j+3)*H1 + hh];
        ushort2 f0 = *(const ushort2*)(ftb + (size_t)u0 * HD + lane * 2);
        ushort2 f1 = *(const ushort2*)(ftb + (size_t)u1 * HD + lane * 2);
        ushort2 f2 = *(const ushort2*)(ftb + (size_t)u2 * HD + lane * 2);
        ushort2 f3 = *(const ushort2*)(ftb + (size_t)u3 * HD + lane * 2);
        ax = fmaf(w0, bf2f(f0.x), ax); ay = fmaf(w0, bf2f(f0.y), ay);
        ax = fmaf(w1, bf2f(f1.x), ax); ay = fmaf(w1, bf2f(f1.y), ay);
        ax = fmaf(w2, bf2f(f2.x), ax); ay = fmaf(w2, bf2f(f2.y), ay);
        ax = fmaf(w3, bf2f(f3.x), ax); ay = fmaf(w3, bf2f(f3.y), ay);
        ssum += (w0 + w1) + (w2 + w3);
    }
    for (; j < je; ++j) {
        int u0 = csrp[j] & 0xffff;
        float w0 = exw[(size_t)j*H1 + hh];
        ushort2 f0 = *(const ushort2*)(ftb + (size_t)u0 * HD + lane * 2);
        ax = fmaf(w0, bf2f(f0.x), ax); ay = fmaf(w0, bf2f(f0.y), ay);
        ssum += w0;
    }
    float inv = 1.0f / fmaxf(ssum, 1e-9f);
    h1b[(size_t)w * 64 + lane] = (unsigned)f2bf(ax * inv)
                               | ((unsigned)f2bf(ay * inv) << 16);
}

// ---------------------------------------------------------------------------
// BN stats on bf16 h1
// ---------------------------------------------------------------------------
__global__ void bnstats_k(const unsigned short* __restrict__ h1b,
                          float* __restrict__ sums, float* __restrict__ sumsq) {
    int c = threadIdx.x;  // 128 threads
    float acc = 0.f, acc2 = 0.f;
    for (int r = blockIdx.x; r < N_NODES; r += gridDim.x) {
        float v = bf2f(h1b[(size_t)r * HD + c]);
        acc += v; acc2 += v * v;
    }
    atomicAdd(&sums[c], acc);
    atomicAdd(&sumsq[c], acc2);
}

// ---------------------------------------------------------------------------
// layer-2 gather fused with log_softmax
// ---------------------------------------------------------------------------
__global__ __launch_bounds__(256) void gather2_k(const u64* __restrict__ rowp,
                                                 const unsigned* __restrict__ csrp,
                                                 const float* __restrict__ exw,
                                                 const unsigned short* __restrict__ ft2b,
                                                 float* __restrict__ out) {
    int w = (blockIdx.x * blockDim.x + threadIdx.x) >> 6;   // node
    if (w >= N_NODES) return;
    int lane = threadIdx.x & 63;
    u64 rp = rowp[w];
    int jb = (int)(rp & 0xffffffffu), je = jb + (int)(rp >> 32);
    float acc = 0.f, ssum = 0.f;
    int j = jb;
    for (; j + 3 < je; j += 4) {
        int u0 = csrp[j] & 0xffff, u1 = csrp[j+1] & 0xffff;
        int u2 = csrp[j+2] & 0xffff, u3 = csrp[j+3] & 0xffff;
        float w0 = exw[j], w1 = exw[j+1], w2 = exw[j+2], w3 = exw[j+3];
        float fa = (lane < NC) ? bf2f(ft2b[(size_t)u0 * NC + lane]) : 0.f;
        float fb = (lane < NC) ? bf2f(ft2b[(size_t)u1 * NC + lane]) : 0.f;
        float fc = (lane < NC) ? bf2f(ft2b[(size_t)u2 * NC + lane]) : 0.f;
        float fd = (lane < NC) ? bf2f(ft2b[(size_t)u3 * NC + lane]) : 0.f;
        acc = fmaf(w0, fa, acc); acc = fmaf(w1, fb, acc);
        acc = fmaf(w2, fc, acc); acc = fmaf(w3, fd, acc);
        ssum += (w0 + w1) + (w2 + w3);
    }
    for (; j < je; ++j) {
        int u0 = csrp[j] & 0xffff;
        float w0 = exw[j];
        float fa = (lane < NC) ? bf2f(ft2b[(size_t)u0 * NC + lane]) : 0.f;
        acc = fmaf(w0, fa, acc);
        ssum += w0;
    }
    float v = acc / fmaxf(ssum, 1e-9f);
    float vv = (lane < NC) ? v : -INFINITY;
    float m = vv;
    #pragma unroll
    for (int off = 32; off; off >>= 1) m = fmaxf(m, __shfl_xor(m, off));
    float ex2 = (lane < NC) ? __expf(vv - m) : 0.f;
    float sum = ex2;
    #pragma unroll
    for (int off = 32; off; off >>= 1) sum += __shfl_xor(sum, off);
    if (lane < NC) out[(size_t)w * NC + lane] = vv - m - logf(sum);
}

// ---------------------------------------------------------------------------
extern "C" void kernel_launch(void* const* d_in, const int* in_sizes, int n_in,
                              void* d_out, int out_size, void* d_ws, size_t ws_size,
                              hipStream_t stream) {
    const float* x     = (const float*)d_in[0];
    const int*   src   = (const int*)  d_in[1];
    const int*   dst   = (const int*)  d_in[2];
    const float* W1    = (const float*)d_in[3];
    const float* al1   = (const float*)d_in[4];
    const float* ar1   = (const float*)d_in[5];
    const float* gamma = (const float*)d_in[6];
    const float* beta  = (const float*)d_in[7];
    const float* W2    = (const float*)d_in[8];
    const float* al2   = (const float*)d_in[9];
    const float* ar2   = (const float*)d_in[10];
    float* out = (float*)d_out;

    const size_t NSLOT = (size_t)NBIN * BCAP;          // 1,201,152 compact slots
    const size_t NTMP  = (size_t)NBIN * NREP * RCAP;   // 3,203,072 tmp slots

    char* ws = (char*)d_ws;
    size_t o = 0;
    auto allocB = [&](size_t bytes) { void* p = ws + o; o += (bytes + 15) & ~15ull; return p; };
    // ---- zeroed region (one ~100KB memset) ----
    int*   bincur = (int*)allocB((size_t)NBIN * NREP * 4);
    float* bnsum  = (float*)allocB(HD * 4);
    float* bnsq   = (float*)allocB(HD * 4);
    size_t zeroBytes = o;
    // ---- uninitialized region ----
    unsigned* tmp  = (unsigned*)allocB(NTMP * 4);
    unsigned* csrp = (unsigned*)allocB(NSLOT * 4);
    int*   bintot  = (int*)allocB(NBIN * 4);
    u64*   rowp    = (u64*)allocB((size_t)N_NODES * 8);
    float4* exw1   = (float4*)allocB(NSLOT * 16);
    float*  exw2   = (float*)allocB(NSLOT * 4);
    unsigned short* w1t  = (unsigned short*)allocB((size_t)IN_DIM * HD * 2);
    unsigned short* w2t  = (unsigned short*)allocB((size_t)48 * HD * 2);
    unsigned short* ft1b = (unsigned short*)allocB((size_t)N_NODES * HD * 2);
    unsigned int*   h1b  = (unsigned int*)allocB((size_t)N_NODES * HD * 2);
    float* el1  = (float*)allocB(N_NODES * H1 * 4);
    float* er1  = (float*)allocB(N_NODES * H1 * 4);
    unsigned short* ft2b = (unsigned short*)allocB((size_t)N_NODES * NC * 2);
    float* el2  = (float*)allocB(N_NODES * 4);
    float* er2  = (float*)allocB(N_NODES * 4);

    hipMemsetAsync(d_ws, 0, zeroBytes, stream);

    const int NB_E = (N_EDGES + 255) / 256;            // 3321
    const int NB_G = (N_NODES + 63) / 64;              // 782
    const int NB_S = (int)(NSLOT / 256);               // 4692 (BCAP%256==0)

    // CSR build (binned, edge-id-sharded cursors) + weight cvt
    binscatter_k<<<NB_E, 256, 0, stream>>>(src, dst, bincur, tmp, W1, W2, w1t, w2t);
    binsort_k<<<NBIN, 256, 0, stream>>>(tmp, bincur, csrp, rowp, bintot);

    // layer 1
    mfma1_k<<<NB_G, 256, 0, stream>>>(x, w1t, ft1b);
    eler1b_k<<<(N_NODES * H1 + 255) / 256, 256, 0, stream>>>(ft1b, al1, ar1, el1, er1);
    exw1_k<<<NB_S, 256, 0, stream>>>(csrp, bintot, el1, er1, exw1);
    gather1_k<<<N_NODES / 4, 256, 0, stream>>>(rowp, csrp, (const float*)exw1, ft1b, h1b);

    bnstats_k<<<512, HD, 0, stream>>>((const unsigned short*)h1b, bnsum, bnsq);

    // layer 2 (BN fold + ELU fused into GEMM2 A-staging)
    mfma2_k<<<NB_G, 256, 0, stream>>>((const unsigned short*)h1b, w2t,
                                      bnsum, bnsq, gamma, beta, ft2b);
    eler2b_k<<<(N_NODES + 255) / 256, 256, 0, stream>>>(ft2b, al2, ar2, el2, er2);
    exw2_k<<<NB_S, 256, 0, stream>>>(csrp, bintot, el2, er2, exw2);
    gather2_k<<<N_NODES / 4, 256, 0, stream>>>(rowp, csrp, exw2, ft2b, out);
}

// Round 10
// 347.232 us; speedup vs baseline: 1.5176x; 1.0160x over previous
//
#include <hip/hip_runtime.h>
#include <hip/hip_bf16.h>
#include <math.h>

#define N_NODES 50000
#define N_EDGES 850000
#define IN_DIM  256
#define HD      128      // H1*D
#define H1      4
#define D       32
#define NC      40       // num classes
#define SLOPE   0.2f
#define EPS_BN  1e-5f

#define NBIN    782      // ceil(50000/64) destination bins of 64 nodes
#define BCAP    1536     // compact slots per bin (mean 1088, sigma ~33)
#define NREP    32       // cursor replicas per bin (kills atomic contention)
#define RCAP    128      // slots per (bin,replica): rep=e&31 -> mean 34, sigma 5.8
#define NWAVE   4        // waves per 256-thread block (binsort strides by THIS)

typedef __attribute__((ext_vector_type(8))) short bf16x8;
typedef __attribute__((ext_vector_type(4))) float f32x4;
typedef unsigned long long u64;

__device__ __forceinline__ unsigned short f2bf(float x) {
    union { float f; unsigned u; } v; v.f = x;
    unsigned r = v.u + 0x7FFF + ((v.u >> 16) & 1);   // RNE
    return (unsigned short)(r >> 16);
}
__device__ __forceinline__ float bf2f(unsigned short h) {
    union { unsigned u; float f; } v; v.u = ((unsigned)h) << 16;
    return v.f;
}
__device__ __forceinline__ uint4 pack8(float a0,float a1,float a2,float a3,
                                       float a4,float a5,float a6,float a7) {
    uint4 p;
    p.x = f2bf(a0) | ((unsigned)f2bf(a1) << 16);
    p.y = f2bf(a2) | ((unsigned)f2bf(a3) << 16);
    p.z = f2bf(a4) | ((unsigned)f2bf(a5) << 16);
    p.w = f2bf(a6) | ((unsigned)f2bf(a7) << 16);
    return p;
}

// chunk-swizzled [rows][32] bf16 tile: 4 chunks of 8 bf16 per row (64B rows).
__device__ __forceinline__ int tile32_addr(int row, int chunk) {
    return row * 32 + ((chunk ^ ((row >> 1) & 3)) << 3);
}

// ---------------------------------------------------------------------------
// binscatter (+ weight cvt): edge e -> tmp[(bin*NREP + (e&31))*RCAP + cur]
// packed u32 (dlow<<16 | src). 25k sharded cursors, ~34 hits each.
// ---------------------------------------------------------------------------
__global__ __launch_bounds__(256) void binscatter_k(const int* __restrict__ src,
                                                    const int* __restrict__ dst,
                                                    int* __restrict__ bincur,
                                                    unsigned* __restrict__ tmp,
                                                    const float* __restrict__ W1,
                                                    const float* __restrict__ W2,
                                                    unsigned short* __restrict__ W1t,
                                                    unsigned short* __restrict__ W2t) {
    int e = blockIdx.x * blockDim.x + threadIdx.x;
    if (e < IN_DIM * HD) {                 // W1 [256][128] -> W1t [128][256]
        int k = e >> 7, n = e & 127;
        W1t[n * IN_DIM + k] = f2bf(W1[e]);
    }
    if (e < 48 * HD) {                     // W2 [128][40] -> W2t [48][128]
        int n = e >> 7, k = e & 127;
        float v = (n < NC) ? W2[k * NC + n] : 0.f;
        W2t[e] = f2bf(v);
    }
    if (e >= N_EDGES) return;
    int v = dst[e];
    int b = v >> 6;
    int rep = e & (NREP - 1);              // edge-id based: decorrelated from data order
    int cell = b * NREP + rep;
    int cur = atomicAdd(&bincur[cell], 1);
    if (cur < RCAP)
        tmp[(size_t)cell * RCAP + cur] = ((unsigned)(v & 63) << 16) | (unsigned)src[e];
}

// ---------------------------------------------------------------------------
// binsort: one block (4 waves) per bin. Reads the bin's 32 ragged segments
// (wave wv owns s = wv, wv+NWAVE, ...), LDS hist over 64 nodes + wave scan ->
// compact csrp, packed rowp (start | deg<<32), bintot.
// ---------------------------------------------------------------------------
__global__ __launch_bounds__(256) void binsort_k(const unsigned* __restrict__ tmp,
                                                 const int* __restrict__ bincur,
                                                 unsigned* __restrict__ csrp,
                                                 u64* __restrict__ rowp,
                                                 int* __restrict__ bintot) {
    __shared__ int cnts[NREP];
    __shared__ int hist[64];
    __shared__ int cur[64];
    int b = blockIdx.x, tid = threadIdx.x;
    int nbase = b << 6;
    size_t cbase = (size_t)b * BCAP;
    int wv = tid >> 6, ln = tid & 63;
    if (tid < NREP) cnts[tid] = min(bincur[b * NREP + tid], RCAP);
    if (tid < 64) hist[tid] = 0;
    __syncthreads();
    // pass 1: histogram (stride = NWAVE waves!)
    for (int s = wv; s < NREP; s += NWAVE) {
        int c = cnts[s];
        const unsigned* seg = tmp + (size_t)(b * NREP + s) * RCAP;
        for (int t = ln; t < c; t += 64)
            atomicAdd(&hist[seg[t] >> 16], 1);
    }
    __syncthreads();
    if (tid < 64) {
        int h = hist[tid];
        int v = h;
        #pragma unroll
        for (int off = 1; off < 64; off <<= 1) {
            int t2 = __shfl_up(v, off);
            if (tid >= off) v += t2;
        }
        int excl = v - h;
        cur[tid] = excl;
        int node = nbase + tid;
        if (node < N_NODES)
            rowp[node] = ((u64)h << 32) | (unsigned)(cbase + excl);
        if (tid == 63) bintot[b] = v;
    }
    __syncthreads();
    // pass 2: scatter into compact bin region (stride = NWAVE)
    for (int s = wv; s < NREP; s += NWAVE) {
        int c = cnts[s];
        const unsigned* seg = tmp + (size_t)(b * NREP + s) * RCAP;
        for (int t = ln; t < c; t += 64) {
            unsigned p = seg[t];
            int pos = atomicAdd(&cur[p >> 16], 1);
            csrp[cbase + pos] = p;
        }
    }
}

// ---------------------------------------------------------------------------
// MFMA GEMM1: ft1b = bf16( bf16(x) @ bf16(W1) ).  M=50000, K=256, N=128.
// ---------------------------------------------------------------------------
__global__ __launch_bounds__(256) void mfma1_k(const float* __restrict__ X,
                                               const unsigned short* __restrict__ W1t,
                                               unsigned short* __restrict__ ftb) {
    __shared__ unsigned short alds[2][64 * 32];
    __shared__ unsigned short wlds[2][128 * 32];
    const int tid = threadIdx.x;
    const int lane = tid & 63, wid = tid >> 6;
    const int wr = wid >> 1, wc = wid & 1;
    const int rowBase = blockIdx.x * 64;
    const int s_arow = tid >> 2, s_ac = tid & 3;
    const int s_wcol = tid >> 1, s_wc0 = (tid & 1) * 2;

    auto stageA = [&](int buf, int ks) {
        float4 v0 = make_float4(0.f,0.f,0.f,0.f), v1 = v0;
        int gr = rowBase + s_arow;
        if (gr < N_NODES) {
            const float4* p = (const float4*)(X + (size_t)gr * IN_DIM + ks * 32 + s_ac * 8);
            v0 = p[0]; v1 = p[1];
        }
        *(uint4*)&alds[buf][tile32_addr(s_arow, s_ac)] =
            pack8(v0.x,v0.y,v0.z,v0.w,v1.x,v1.y,v1.z,v1.w);
    };
    auto stageW = [&](int buf, int ks) {
        const uint4* g = (const uint4*)(W1t + s_wcol * IN_DIM + ks * 32 + s_wc0 * 8);
        uint4 a = g[0], b = g[1];
        *(uint4*)&wlds[buf][tile32_addr(s_wcol, s_wc0)] = a;
        *(uint4*)&wlds[buf][tile32_addr(s_wcol, s_wc0 + 1)] = b;
    };

    f32x4 acc[2][4];
    #pragma unroll
    for (int mf = 0; mf < 2; ++mf)
        #pragma unroll
        for (int nf = 0; nf < 4; ++nf)
            acc[mf][nf] = (f32x4){0.f, 0.f, 0.f, 0.f};

    stageA(0, 0); stageW(0, 0);
    for (int ks = 0; ks < 8; ++ks) {
        __syncthreads();
        if (ks < 7) { stageA((ks + 1) & 1, ks + 1); stageW((ks + 1) & 1, ks + 1); }
        int buf = ks & 1;
        bf16x8 afrag[2], bfrag[4];
        #pragma unroll
        for (int mf = 0; mf < 2; ++mf) {
            int row = wr * 32 + mf * 16 + (lane & 15);
            afrag[mf] = *(const bf16x8*)&alds[buf][tile32_addr(row, lane >> 4)];
        }
        #pragma unroll
        for (int nf = 0; nf < 4; ++nf) {
            int col = wc * 64 + nf * 16 + (lane & 15);
            bfrag[nf] = *(const bf16x8*)&wlds[buf][tile32_addr(col, lane >> 4)];
        }
        #pragma unroll
        for (int mf = 0; mf < 2; ++mf)
            #pragma unroll
            for (int nf = 0; nf < 4; ++nf)
                acc[mf][nf] = __builtin_amdgcn_mfma_f32_16x16x32_bf16(
                    afrag[mf], bfrag[nf], acc[mf][nf], 0, 0, 0);
    }
    #pragma unroll
    for (int mf = 0; mf < 2; ++mf) {
        int r0 = rowBase + wr * 32 + mf * 16 + (lane >> 4) * 4;
        #pragma unroll
        for (int nf = 0; nf < 4; ++nf) {
            int col = wc * 64 + nf * 16 + (lane & 15);
            #pragma unroll
            for (int v = 0; v < 4; ++v) {
                int r = r0 + v;
                if (r < N_NODES) ftb[(size_t)r * HD + col] = f2bf(acc[mf][nf][v]);
            }
        }
    }
}

// ---------------------------------------------------------------------------
// MFMA GEMM2: ft2b = bf16( elu(bn(h1b)) @ W2 ). BN fold in prologue.
// ---------------------------------------------------------------------------
__global__ __launch_bounds__(256) void mfma2_k(const unsigned short* __restrict__ Hin,
                                               const unsigned short* __restrict__ W2t,
                                               const float* __restrict__ bnsum,
                                               const float* __restrict__ bnsq,
                                               const float* __restrict__ gamma,
                                               const float* __restrict__ beta,
                                               unsigned short* __restrict__ ft2b) {
    __shared__ unsigned short alds[2][64 * 32];
    __shared__ unsigned short wlds[48 * 128];
    __shared__ float sc_lds[HD], sh_lds[HD];
    const int tid = threadIdx.x;
    const int lane = tid & 63, wid = tid >> 6;
    const int rowBase = blockIdx.x * 64;
    const int s_arow = tid >> 2, s_ac = tid & 3;

    if (tid < HD) {
        const float invN = 1.0f / (float)N_NODES;
        float mu = bnsum[tid] * invN;
        float var = bnsq[tid] * invN - mu * mu;
        float sc = gamma[tid] * rsqrtf(var + EPS_BN);
        sc_lds[tid] = sc;
        sh_lds[tid] = beta[tid] - mu * sc;
    }
    for (int i = tid; i < 48 * 16; i += 256) {
        int col = i >> 4, c = i & 15;
        uint4 v = *(const uint4*)(W2t + col * HD + c * 8);
        *(uint4*)&wlds[col * HD + ((c ^ (col & 7)) << 3)] = v;
    }
    __syncthreads();

    auto stageA = [&](int buf, int ks) {
        int c0 = ks * 32 + s_ac * 8;
        uint4 pv = make_uint4(0,0,0,0);
        int gr = rowBase + s_arow;
        if (gr < N_NODES) pv = *(const uint4*)(Hin + (size_t)gr * HD + c0);
        float4 sc0 = *(const float4*)(sc_lds + c0), sc1 = *(const float4*)(sc_lds + c0 + 4);
        float4 sh0 = *(const float4*)(sh_lds + c0), sh1 = *(const float4*)(sh_lds + c0 + 4);
        float t[8];
        t[0] = fmaf(bf2f(pv.x & 0xffff), sc0.x, sh0.x);
        t[1] = fmaf(bf2f(pv.x >> 16),    sc0.y, sh0.y);
        t[2] = fmaf(bf2f(pv.y & 0xffff), sc0.z, sh0.z);
        t[3] = fmaf(bf2f(pv.y >> 16),    sc0.w, sh0.w);
        t[4] = fmaf(bf2f(pv.z & 0xffff), sc1.x, sh1.x);
        t[5] = fmaf(bf2f(pv.z >> 16),    sc1.y, sh1.y);
        t[6] = fmaf(bf2f(pv.w & 0xffff), sc1.z, sh1.z);
        t[7] = fmaf(bf2f(pv.w >> 16),    sc1.w, sh1.w);
        #pragma unroll
        for (int i = 0; i < 8; ++i) t[i] = t[i] > 0.f ? t[i] : expm1f(t[i]);
        *(uint4*)&alds[buf][tile32_addr(s_arow, s_ac)] =
            pack8(t[0],t[1],t[2],t[3],t[4],t[5],t[6],t[7]);
    };

    f32x4 acc[3];
    #pragma unroll
    for (int nf = 0; nf < 3; ++nf) acc[nf] = (f32x4){0.f, 0.f, 0.f, 0.f};

    stageA(0, 0);
    for (int ks = 0; ks < 4; ++ks) {
        __syncthreads();
        if (ks < 3) stageA((ks + 1) & 1, ks + 1);
        int buf = ks & 1;
        int row = wid * 16 + (lane & 15);
        bf16x8 a = *(const bf16x8*)&alds[buf][tile32_addr(row, lane >> 4)];
        #pragma unroll
        for (int nf = 0; nf < 3; ++nf) {
            int col = nf * 16 + (lane & 15);
            int c = ks * 4 + (lane >> 4);
            bf16x8 b = *(const bf16x8*)&wlds[col * HD + ((c ^ (col & 7)) << 3)];
            acc[nf] = __builtin_amdgcn_mfma_f32_16x16x32_bf16(a, b, acc[nf], 0, 0, 0);
        }
    }
    int r0 = rowBase + wid * 16 + (lane >> 4) * 4;
    #pragma unroll
    for (int nf = 0; nf < 3; ++nf) {
        int col = nf * 16 + (lane & 15);
        if (col < NC) {
            #pragma unroll
            for (int v = 0; v < 4; ++v) {
                int r = r0 + v;
                if (r < N_NODES) ft2b[(size_t)r * NC + col] = f2bf(acc[nf][v]);
            }
        }
    }
}

// ---------------------------------------------------------------------------
// el/er layer 1 from bf16 features
// ---------------------------------------------------------------------------
__global__ void eler1b_k(const unsigned short* __restrict__ ftb,
                         const float* __restrict__ alw, const float* __restrict__ arw,
                         float* __restrict__ el, float* __restrict__ er) {
    int t = blockIdx.x * blockDim.x + threadIdx.x;
    if (t >= N_NODES * H1) return;
    int n = t >> 2, h = t & 3;
    const unsigned short* f = ftb + (size_t)n * HD + h * D;
    const float* a = alw + h * D;
    const float* r = arw + h * D;
    float sl = 0.f, sr = 0.f;
    #pragma unroll
    for (int d = 0; d < D; d += 8) {
        uint4 fv = *(const uint4*)(f + d);
        float x0 = bf2f(fv.x & 0xffff), x1 = bf2f(fv.x >> 16);
        float x2 = bf2f(fv.y & 0xffff), x3 = bf2f(fv.y >> 16);
        float x4 = bf2f(fv.z & 0xffff), x5 = bf2f(fv.z >> 16);
        float x6 = bf2f(fv.w & 0xffff), x7 = bf2f(fv.w >> 16);
        sl += x0*a[d] + x1*a[d+1] + x2*a[d+2] + x3*a[d+3]
            + x4*a[d+4] + x5*a[d+5] + x6*a[d+6] + x7*a[d+7];
        sr += x0*r[d] + x1*r[d+1] + x2*r[d+2] + x3*r[d+3]
            + x4*r[d+4] + x5*r[d+5] + x6*r[d+6] + x7*r[d+7];
    }
    el[t] = sl; er[t] = sr;
}

// el/er for layer 2 from bf16 ft2
__global__ void eler2b_k(const unsigned short* __restrict__ ft2b,
                         const float* __restrict__ alw, const float* __restrict__ arw,
                         float* __restrict__ el, float* __restrict__ er) {
    int n = blockIdx.x * blockDim.x + threadIdx.x;
    if (n >= N_NODES) return;
    const unsigned short* f = ft2b + (size_t)n * NC;
    float sl = 0.f, sr = 0.f;
    #pragma unroll
    for (int d = 0; d < NC; d += 4) {
        uint2 fv = *(const uint2*)(f + d);
        float x0 = bf2f(fv.x & 0xffff), x1 = bf2f(fv.x >> 16);
        float x2 = bf2f(fv.y & 0xffff), x3 = bf2f(fv.y >> 16);
        sl += x0*alw[d] + x1*alw[d+1] + x2*alw[d+2] + x3*alw[d+3];
        sr += x0*arw[d] + x1*arw[d+1] + x2*arw[d+2] + x3*arw[d+3];
    }
    el[n] = sl; er[n] = sr;
}

// ---------------------------------------------------------------------------
// layer-1 gather, fused attention weights: one wave per dst node; lane owns
// bf16x2 of 128 dims, head hh = lane>>4. exp computed inline (el L2-resident).
// Unroll 8 for deep MLP. Writes bf16 h1.
// ---------------------------------------------------------------------------
__global__ __launch_bounds__(256) void gather1_k(const u64* __restrict__ rowp,
                                                 const unsigned* __restrict__ csrp,
                                                 const float* __restrict__ el,
                                                 const float* __restrict__ er,
                                                 const unsigned short* __restrict__ ftb,
                                                 unsigned int* __restrict__ h1b) {
    int w = (blockIdx.x * blockDim.x + threadIdx.x) >> 6;   // node
    if (w >= N_NODES) return;
    int lane = threadIdx.x & 63;
    int hh = lane >> 4;
    float erv = er[w * H1 + hh];
    u64 rp = rowp[w];
    int jb = (int)(rp & 0xffffffffu), je = jb + (int)(rp >> 32);
    float ax = 0.f, ay = 0.f, ssum = 0.f;
    int j = jb;
    for (; j + 7 < je; j += 8) {
        int u[8]; float wv[8]; ushort2 f[8];
        #pragma unroll
        for (int k = 0; k < 8; ++k) u[k] = csrp[j + k] & 0xffff;
        #pragma unroll
        for (int k = 0; k < 8; ++k)
            f[k] = *(const ushort2*)(ftb + (size_t)u[k] * HD + lane * 2);
        #pragma unroll
        for (int k = 0; k < 8; ++k) {
            float t = el[u[k] * H1 + hh] + erv;
            t = t > 0.f ? t : SLOPE * t;
            wv[k] = __expf(t);
        }
        #pragma unroll
        for (int k = 0; k < 8; ++k) {
            ax = fmaf(wv[k], bf2f(f[k].x), ax);
            ay = fmaf(wv[k], bf2f(f[k].y), ay);
            ssum += wv[k];
        }
    }
    for (; j < je; ++j) {
        int u0 = csrp[j] & 0xffff;
        float t = el[u0 * H1 + hh] + erv;
        t = t > 0.f ? t : SLOPE * t;
        float w0 = __expf(t);
        ushort2 f0 = *(const ushort2*)(ftb + (size_t)u0 * HD + lane * 2);
        ax = fmaf(w0, bf2f(f0.x), ax); ay = fmaf(w0, bf2f(f0.y), ay);
        ssum += w0;
    }
    float inv = 1.0f / fmaxf(ssum, 1e-9f);
    h1b[(size_t)w * 64 + lane] = (unsigned)f2bf(ax * inv)
                               | ((unsigned)f2bf(ay * inv) << 16);
}

// ---------------------------------------------------------------------------
// BN stats on bf16 h1
// ---------------------------------------------------------------------------
__global__ void bnstats_k(const unsigned short* __restrict__ h1b,
                          float* __restrict__ sums, float* __restrict__ sumsq) {
    int c = threadIdx.x;  // 128 threads
    float acc = 0.f, acc2 = 0.f;
    for (int r = blockIdx.x; r < N_NODES; r += gridDim.x) {
        float v = bf2f(h1b[(size_t)r * HD + c]);
        acc += v; acc2 += v * v;
    }
    atomicAdd(&sums[c], acc);
    atomicAdd(&sumsq[c], acc2);
}

// ---------------------------------------------------------------------------
// layer-2 gather, fused attention weights + log_softmax. Unroll 8.
// ---------------------------------------------------------------------------
__global__ __launch_bounds__(256) void gather2_k(const u64* __restrict__ rowp,
                                                 const unsigned* __restrict__ csrp,
                                                 const float* __restrict__ el,
                                                 const float* __restrict__ er,
                                                 const unsigned short* __restrict__ ft2b,
                                                 float* __restrict__ out) {
    int w = (blockIdx.x * blockDim.x + threadIdx.x) >> 6;   // node
    if (w >= N_NODES) return;
    int lane = threadIdx.x & 63;
    float erv = er[w];
    u64 rp = rowp[w];
    int jb = (int)(rp & 0xffffffffu), je = jb + (int)(rp >> 32);
    float acc = 0.f, ssum = 0.f;
    int j = jb;
    for (; j + 7 < je; j += 8) {
        int u[8]; float wv[8]; float fv[8];
        #pragma unroll
        for (int k = 0; k < 8; ++k) u[k] = csrp[j + k] & 0xffff;
        #pragma unroll
        for (int k = 0; k < 8; ++k)
            fv[k] = (lane < NC) ? bf2f(ft2b[(size_t)u[k] * NC + lane]) : 0.f;
        #pragma unroll
        for (int k = 0; k < 8; ++k) {
            float t = el[u[k]] + erv;
            t = t > 0.f ? t : SLOPE * t;
            wv[k] = __expf(t);
        }
        #pragma unroll
        for (int k = 0; k < 8; ++k) {
            acc = fmaf(wv[k], fv[k], acc);
            ssum += wv[k];
        }
    }
    for (; j < je; ++j) {
        int u0 = csrp[j] & 0xffff;
        float t = el[u0] + erv;
        t = t > 0.f ? t : SLOPE * t;
        float w0 = __expf(t);
        float fa = (lane < NC) ? bf2f(ft2b[(size_t)u0 * NC + lane]) : 0.f;
        acc = fmaf(w0, fa, acc);
        ssum += w0;
    }
    float v = acc / fmaxf(ssum, 1e-9f);
    float vv = (lane < NC) ? v : -INFINITY;
    float m = vv;
    #pragma unroll
    for (int off = 32; off; off >>= 1) m = fmaxf(m, __shfl_xor(m, off));
    float ex2 = (lane < NC) ? __expf(vv - m) : 0.f;
    float sum = ex2;
    #pragma unroll
    for (int off = 32; off; off >>= 1) sum += __shfl_xor(sum, off);
    if (lane < NC) out[(size_t)w * NC + lane] = vv - m - logf(sum);
}

// ---------------------------------------------------------------------------
extern "C" void kernel_launch(void* const* d_in, const int* in_sizes, int n_in,
                              void* d_out, int out_size, void* d_ws, size_t ws_size,
                              hipStream_t stream) {
    const float* x     = (const float*)d_in[0];
    const int*   src   = (const int*)  d_in[1];
    const int*   dst   = (const int*)  d_in[2];
    const float* W1    = (const float*)d_in[3];
    const float* al1   = (const float*)d_in[4];
    const float* ar1   = (const float*)d_in[5];
    const float* gamma = (const float*)d_in[6];
    const float* beta  = (const float*)d_in[7];
    const float* W2    = (const float*)d_in[8];
    const float* al2   = (const float*)d_in[9];
    const float* ar2   = (const float*)d_in[10];
    float* out = (float*)d_out;

    const size_t NSLOT = (size_t)NBIN * BCAP;          // 1,201,152 compact slots
    const size_t NTMP  = (size_t)NBIN * NREP * RCAP;   // 3,203,072 tmp slots

    char* ws = (char*)d_ws;
    size_t o = 0;
    auto allocB = [&](size_t bytes) { void* p = ws + o; o += (bytes + 15) & ~15ull; return p; };
    // ---- zeroed region (one ~100KB memset) ----
    int*   bincur = (int*)allocB((size_t)NBIN * NREP * 4);
    float* bnsum  = (float*)allocB(HD * 4);
    float* bnsq   = (float*)allocB(HD * 4);
    size_t zeroBytes = o;
    // ---- uninitialized region ----
    unsigned* tmp  = (unsigned*)allocB(NTMP * 4);
    unsigned* csrp = (unsigned*)allocB(NSLOT * 4);
    int*   bintot  = (int*)allocB(NBIN * 4);
    u64*   rowp    = (u64*)allocB((size_t)N_NODES * 8);
    unsigned short* w1t  = (unsigned short*)allocB((size_t)IN_DIM * HD * 2);
    unsigned short* w2t  = (unsigned short*)allocB((size_t)48 * HD * 2);
    unsigned short* ft1b = (unsigned short*)allocB((size_t)N_NODES * HD * 2);
    unsigned int*   h1b  = (unsigned int*)allocB((size_t)N_NODES * HD * 2);
    float* el1  = (float*)allocB(N_NODES * H1 * 4);
    float* er1  = (float*)allocB(N_NODES * H1 * 4);
    unsigned short* ft2b = (unsigned short*)allocB((size_t)N_NODES * NC * 2);
    float* el2  = (float*)allocB(N_NODES * 4);
    float* er2  = (float*)allocB(N_NODES * 4);

    hipMemsetAsync(d_ws, 0, zeroBytes, stream);

    const int NB_E = (N_EDGES + 255) / 256;            // 3321
    const int NB_G = (N_NODES + 63) / 64;              // 782

    // CSR build (binned, edge-id-sharded cursors) + weight cvt
    binscatter_k<<<NB_E, 256, 0, stream>>>(src, dst, bincur, tmp, W1, W2, w1t, w2t);
    binsort_k<<<NBIN, 256, 0, stream>>>(tmp, bincur, csrp, rowp, bintot);

    // layer 1
    mfma1_k<<<NB_G, 256, 0, stream>>>(x, w1t, ft1b);
    eler1b_k<<<(N_NODES * H1 + 255) / 256, 256, 0, stream>>>(ft1b, al1, ar1, el1, er1);
    gather1_k<<<N_NODES / 4, 256, 0, stream>>>(rowp, csrp, el1, er1, ft1b, h1b);

    bnstats_k<<<512, HD, 0, stream>>>((const unsigned short*)h1b, bnsum, bnsq);

    // layer 2 (BN fold + ELU fused into GEMM2 A-staging)
    mfma2_k<<<NB_G, 256, 0, stream>>>((const unsigned short*)h1b, w2t,
                                      bnsum, bnsq, gamma, beta, ft2b);
    eler2b_k<<<(N_NODES + 255) / 256, 256, 0, stream>>>(ft2b, al2, ar2, el2, er2);
    gather2_k<<<N_NODES / 4, 256, 0, stream>>>(rowp, csrp, el2, er2, ft2b, out);
}